// Round 1
// baseline (193.366 us; speedup 1.0000x reference)
//
#include <hip/hip_runtime.h>

#define B_ 4
#define C_ 128
#define H_ 128
#define W_ 256
#define HW_ (H_ * W_)
#define ND 81
#define TH 8          // output rows per block
#define TW 16         // output cols per block
#define HR 16         // f2 halo rows  (TH + 8)
#define WCOL 32       // f2 halo cols  (covers N-tile1 reads)
#define KC 32         // channels per LDS chunk (= MFMA K)
#define NCHUNK (C_ / KC)
#define NTHREADS 512

typedef short bf16x8 __attribute__((ext_vector_type(8)));
typedef float f32x4 __attribute__((ext_vector_type(4)));

// LDS layout: pixel-pair rows of 128 B (2 pixels x 32ch x 2B), XOR-swizzled
// byte bits 4..6 with (row & 7) -> bijective, spreads b128 frag reads over all banks.
__device__ __forceinline__ int swz(int p, int byteInHalf) {
    int r = p >> 1;
    int base = (r << 7) + ((p & 1) << 6) + byteInHalf;
    return base ^ ((r & 7) << 4);
}

// fp32 -> bf16 round-to-nearest-even (finite inputs only)
__device__ __forceinline__ unsigned int pack_bf16(float a, float b) {
    unsigned int ua = __float_as_uint(a);
    unsigned int ub = __float_as_uint(b);
    ua = (ua + 0x7FFFu + ((ua >> 16) & 1u)) >> 16;
    ub = (ub + 0x7FFFu + ((ub >> 16) & 1u)) >> 16;
    return (ub << 16) | (ua & 0xFFFFu);
}

__global__ __launch_bounds__(NTHREADS)
void corr81_kernel(const float* __restrict__ f1g, const float* __restrict__ f2g,
                   float* __restrict__ out) {
    __shared__ __align__(16) unsigned short f2s[HR * WCOL * KC];
    __shared__ __align__(16) unsigned short f1s[TH * TW * KC];
    __shared__ float invn2[HR * WCOL];
    __shared__ float invn1[TH * TW];

    const int tid  = threadIdx.x;
    const int lane = tid & 63;
    const int wave = tid >> 6;            // 0..7 -> output row within tile
    const int col  = lane & 15;           // MFMA row/col lane index
    const int quad = lane >> 4;           // MFMA k-quadrant

    const int w0 = blockIdx.x * TW;
    const int h0 = blockIdx.y * TH;
    const int b  = blockIdx.z;
    const size_t inBase = (size_t)b * C_ * HW_;

    // ---- staging assignments ----
    // f2 halo: 512 pixels, one per thread
    const int p2  = tid;
    const int hh2 = p2 >> 5, ww2 = p2 & 31;
    const int gh2 = h0 - 4 + hh2, gw2 = w0 - 4 + ww2;
    const bool v2 = (gh2 >= 0) && (gh2 < H_) && (gw2 >= 0) && (gw2 < W_);
    const float* src2 = f2g + inBase + (size_t)(v2 ? gh2 : 0) * W_ + (v2 ? gw2 : 0);
    float ss2 = 0.f;

    // f1 tile: 128 pixels, threads 0..127 double-duty
    const int p1  = tid & 127;
    const int hh1 = p1 >> 4, ww1 = p1 & 15;
    const float* src1 = f1g + inBase + (size_t)(h0 + hh1) * W_ + (w0 + ww1);
    float ss1 = 0.f;

    const int stag = tid & 7;   // stagger c-order to spread ds_write banks

    // A-fragment address for this wave's M-tile (f1 pixel = wave*16 + col)
    const int aOff = swz(wave * 16 + col, quad * 16);

    f32x4 acc[9][2];
#pragma unroll
    for (int d = 0; d < 9; ++d) {
        acc[d][0] = (f32x4)0.f;
        acc[d][1] = (f32x4)0.f;
    }

    char* f2sW = (char*)f2s;
    char* f1sW = (char*)f1s;
    const char* f2sR = (const char*)f2s;
    const char* f1sR = (const char*)f1s;

    for (int ch = 0; ch < NCHUNK; ++ch) {
        const int kc0 = ch * KC;
        // ---- stage f2 halo chunk (all 512 threads) ----
#pragma unroll
        for (int jj = 0; jj < 16; ++jj) {
            int j = (jj + stag) & 15;
            int c = kc0 + j * 2;
            float a0 = v2 ? src2[(size_t)c * HW_] : 0.f;
            float a1 = v2 ? src2[(size_t)(c + 1) * HW_] : 0.f;
            ss2 += a0 * a0 + a1 * a1;
            *(unsigned int*)(f2sW + swz(p2, j * 4)) = pack_bf16(a0, a1);
        }
        // ---- stage f1 tile chunk (threads 0..127) ----
        if (tid < 128) {
#pragma unroll
            for (int jj = 0; jj < 16; ++jj) {
                int j = (jj + stag) & 15;
                int c = kc0 + j * 2;
                float a0 = src1[(size_t)c * HW_];
                float a1 = src1[(size_t)(c + 1) * HW_];
                ss1 += a0 * a0 + a1 * a1;
                *(unsigned int*)(f1sW + swz(p1, j * 4)) = pack_bf16(a0, a1);
            }
        }
        if (ch == NCHUNK - 1) {
            // all channels seen: publish inverse norms (F.normalize: x / max(||x||, eps))
            invn2[p2] = 1.f / fmaxf(sqrtf(ss2), 1e-12f);
            if (tid < 128) invn1[p1] = 1.f / fmaxf(sqrtf(ss1), 1e-12f);
        }
        __syncthreads();

        // ---- MFMA compute: this wave's output row vs 9 dy rows, 2 N-tiles ----
        bf16x8 af = *(const bf16x8*)(f1sR + aOff);
#pragma unroll
        for (int dy = 0; dy < 9; ++dy) {
            int pb = (wave + dy) * WCOL + col;
            bf16x8 b0 = *(const bf16x8*)(f2sR + swz(pb, quad * 16));
            bf16x8 b1 = *(const bf16x8*)(f2sR + swz(pb + 16, quad * 16));
            acc[dy][0] = __builtin_amdgcn_mfma_f32_16x16x32_bf16(af, b0, acc[dy][0], 0, 0, 0);
            acc[dy][1] = __builtin_amdgcn_mfma_f32_16x16x32_bf16(af, b1, acc[dy][1], 0, 0, 0);
        }
        __syncthreads();
    }

    // ---- epilogue: extract band, rescale, leaky-relu, store ----
    // D mapping (verified): col = lane&15, row = (lane>>4)*4 + reg
    const int hOut = h0 + wave;
    float* outB = out + (size_t)b * ND * HW_ + (size_t)hOut * W_;
    const float scale = 1.f / (float)C_;

#pragma unroll
    for (int dy = 0; dy < 9; ++dy) {
        int hr = wave + dy;
#pragma unroll
        for (int t = 0; t < 2; ++t) {
            float i2 = invn2[hr * WCOL + t * 16 + col];
#pragma unroll
            for (int r = 0; r < 4; ++r) {
                int row = quad * 4 + r;
                int dx = t * 16 + col - row;   // f2 pixel (w0-4+t*16+col) vs f1 pixel (w0+row)
                if (dx >= 0 && dx <= 8) {
                    float v = acc[dy][t][r] * invn1[wave * 16 + row] * i2 * scale;
                    v = (v >= 0.f) ? v : 0.1f * v;
                    outB[(size_t)(dy * 9 + dx) * HW_ + (w0 + row)] = v;
                }
            }
        }
    }
}

extern "C" void kernel_launch(void* const* d_in, const int* in_sizes, int n_in,
                              void* d_out, int out_size, void* d_ws, size_t ws_size,
                              hipStream_t stream) {
    const float* f1 = (const float*)d_in[0];
    const float* f2 = (const float*)d_in[1];
    float* out = (float*)d_out;
    dim3 grid(W_ / TW, H_ / TH, B_);   // 16 x 16 x 4 = 1024 blocks
    corr81_kernel<<<grid, NTHREADS, 0, stream>>>(f1, f2, out);
}

// Round 3
// 88.835 us; speedup vs baseline: 2.1767x; 2.1767x over previous
//
#include <hip/hip_runtime.h>

#define B_ 4
#define C_ 128
#define H_ 128
#define W_ 256
#define HW_ (H_ * W_)
#define ND 81
#define TH 8          // output rows per block
#define TW 16         // output cols per block
#define HR 16         // f2 halo rows  (TH + 8)
#define WCOL 32       // f2 halo cols
#define KC 32         // channels per LDS chunk (= MFMA K)
#define NCHUNK (C_ / KC)
#define NTHREADS 512

typedef short bf16x8 __attribute__((ext_vector_type(8)));
typedef float f32x4 __attribute__((ext_vector_type(4)));
typedef float f32x4v __attribute__((ext_vector_type(4)));
typedef unsigned int u32x4 __attribute__((ext_vector_type(4)));

// LDS layout: pixel-pair rows of 128 B (2 px x 32ch x 2B).
// Swizzle: XOR bits 4..6 of the FULL byte address by (r & 7) << 4, where
// r = px>>1 lives in bits >=7. Bijective (XOR of low bits by a function of
// high bits), and identical for writer and reader. HW-verified in R1.
__device__ __forceinline__ int swz(int px, int byteInHalf) {
    int r = px >> 1;
    int base = (r << 7) + ((px & 1) << 6) + byteInHalf;
    return base ^ ((r & 7) << 4);
}

// fp32 -> bf16 round-to-nearest-even, packed pair (lo = a, hi = b)
__device__ __forceinline__ unsigned int pack_bf16(float a, float b) {
    unsigned int ua = __float_as_uint(a);
    unsigned int ub = __float_as_uint(b);
    ua = (ua + 0x7FFFu + ((ua >> 16) & 1u)) >> 16;
    ub = (ub + 0x7FFFu + ((ub >> 16) & 1u)) >> 16;
    return (ub << 16) | (ua & 0xFFFFu);
}

__device__ __forceinline__ void accum_sq(unsigned int u, float& ss) {
    float lo = __uint_as_float(u << 16);
    float hi = __uint_as_float(u & 0xFFFF0000u);
    ss += lo * lo + hi * hi;
}

__global__ __launch_bounds__(NTHREADS)
void corr81_kernel(const float* __restrict__ f1g, const float* __restrict__ f2g,
                   float* __restrict__ out) {
    __shared__ __align__(16) unsigned short f2s[HR * WCOL * KC];   // 32 KB
    __shared__ __align__(16) unsigned short f1s[TH * TW * KC];     // 8 KB
    __shared__ float invn2[HR * WCOL];
    __shared__ float invn1[TH * TW];

    const int tid  = threadIdx.x;
    const int lane = tid & 63;
    const int wave = tid >> 6;            // 0..7 -> output row within tile
    const int col  = lane & 15;
    const int quad = lane >> 4;

    const int w0 = blockIdx.x * TW;
    const int h0 = blockIdx.y * TH;
    const int b  = blockIdx.z;
    const size_t inBase = (size_t)b * C_ * HW_;

    // ---- f2 staging tasks: (i 0..3) x per-thread (g2, cp2, rq) ----
    const int g2  = tid & 7;              // 4-px group 0..7
    const int cp2 = (tid >> 3) & 15;      // channel pair 0..15 (varies within wave)
    const int rq  = tid >> 7;             // row quarter 0..3
    const int gw2 = w0 - 4 + g2 * 4;
    const bool colok2 = (gw2 >= 0) && (gw2 < W_);

    // ---- f1 staging task: one per thread ----
    const int g1  = tid & 3;
    const int cp1 = (tid >> 2) & 15;
    const int r1  = tid >> 6;             // 0..7
    const float* src1 = f1g + inBase + (size_t)(h0 + r1) * W_ + (w0 + g1 * 4);

    // A-fragment address (f1 pixel = wave*16 + col)
    const int aOff = swz(wave * 16 + col, quad * 16);

    f32x4 acc[9][2];
#pragma unroll
    for (int d = 0; d < 9; ++d) {
        acc[d][0] = (f32x4)0.f;
        acc[d][1] = (f32x4)0.f;
    }

    char* f2sW = (char*)f2s;
    char* f1sW = (char*)f1s;
    const char* f2sR = (const char*)f2s;
    const char* f1sR = (const char*)f1s;

    float ss2 = 0.f, ss1 = 0.f;

    // prefetch registers
    f32x4v A0[4], A1[4], B0, B1;

    // ---- prologue: issue chunk-0 loads ----
#pragma unroll
    for (int i = 0; i < 4; ++i) {
        int r  = i * 4 + rq;
        int gh = h0 - 4 + r;
        if (colok2 && gh >= 0 && gh < H_) {
            const float* s = f2g + inBase + (size_t)(cp2 * 2) * HW_ + (size_t)gh * W_ + gw2;
            A0[i] = *(const f32x4v*)s;
            A1[i] = *(const f32x4v*)(s + HW_);
        } else {
            A0[i] = (f32x4v)0.f;
            A1[i] = (f32x4v)0.f;
        }
    }
    {
        const float* s = src1 + (size_t)(cp1 * 2) * HW_;
        B0 = *(const f32x4v*)s;
        B1 = *(const f32x4v*)(s + HW_);
    }

    for (int ch = 0; ch < NCHUNK; ++ch) {
        // ---- pack + write LDS from prefetch regs ----
#pragma unroll
        for (int i = 0; i < 4; ++i) {
            int r = i * 4 + rq;
#pragma unroll
            for (int j = 0; j < 4; ++j) {
                int px = r * 32 + g2 * 4 + j;
                *(unsigned int*)(f2sW + swz(px, cp2 * 4)) = pack_bf16(A0[i][j], A1[i][j]);
            }
        }
#pragma unroll
        for (int j = 0; j < 4; ++j) {
            int px = r1 * 16 + g1 * 4 + j;
            *(unsigned int*)(f1sW + swz(px, cp1 * 4)) = pack_bf16(B0[j], B1[j]);
        }

        // ---- issue next chunk's loads (stay in flight across compute) ----
        if (ch < NCHUNK - 1) {
            const int kc0 = (ch + 1) * KC;
#pragma unroll
            for (int i = 0; i < 4; ++i) {
                int r  = i * 4 + rq;
                int gh = h0 - 4 + r;
                if (colok2 && gh >= 0 && gh < H_) {
                    const float* s = f2g + inBase + (size_t)(kc0 + cp2 * 2) * HW_ + (size_t)gh * W_ + gw2;
                    A0[i] = *(const f32x4v*)s;
                    A1[i] = *(const f32x4v*)(s + HW_);
                } else {
                    A0[i] = (f32x4v)0.f;
                    A1[i] = (f32x4v)0.f;
                }
            }
            const float* s = src1 + (size_t)(kc0 + cp1 * 2) * HW_;
            B0 = *(const f32x4v*)s;
            B1 = *(const f32x4v*)(s + HW_);
        }

        __syncthreads();

        // ---- norm accumulation from bf16 LDS ----
        // f2: thread tid owns pixel tid (32 ch this chunk)
#pragma unroll
        for (int j = 0; j < 4; ++j) {
            u32x4 v = *(const u32x4*)(f2sR + swz(tid, j * 16));
            accum_sq(v[0], ss2); accum_sq(v[1], ss2);
            accum_sq(v[2], ss2); accum_sq(v[3], ss2);
        }
        // f1: 4 threads per pixel, each one b128
        {
            u32x4 v = *(const u32x4*)(f1sR + swz(tid >> 2, (tid & 3) * 16));
            accum_sq(v[0], ss1); accum_sq(v[1], ss1);
            accum_sq(v[2], ss1); accum_sq(v[3], ss1);
        }
        if (ch == NCHUNK - 1) {
            invn2[tid] = 1.f / fmaxf(sqrtf(ss2), 1e-12f);
            float t1 = ss1 + __shfl_xor(ss1, 1);
            t1 += __shfl_xor(t1, 2);
            if ((tid & 3) == 0) invn1[tid >> 2] = 1.f / fmaxf(sqrtf(t1), 1e-12f);
        }

        // ---- MFMA: this wave's f1 row vs 9 dy rows, 2 N-tiles ----
        bf16x8 af = *(const bf16x8*)(f1sR + aOff);
#pragma unroll
        for (int dy = 0; dy < 9; ++dy) {
            int pb = (wave + dy) * WCOL + col;
            bf16x8 b0 = *(const bf16x8*)(f2sR + swz(pb, quad * 16));
            bf16x8 b1 = *(const bf16x8*)(f2sR + swz(pb + 16, quad * 16));
            acc[dy][0] = __builtin_amdgcn_mfma_f32_16x16x32_bf16(af, b0, acc[dy][0], 0, 0, 0);
            acc[dy][1] = __builtin_amdgcn_mfma_f32_16x16x32_bf16(af, b1, acc[dy][1], 0, 0, 0);
        }
        __syncthreads();
    }

    // ---- epilogue: extract band, rescale, leaky-relu, store ----
    const int hOut = h0 + wave;
    float* outB = out + (size_t)b * ND * HW_ + (size_t)hOut * W_;
    const float scale = 1.f / (float)C_;

#pragma unroll
    for (int dy = 0; dy < 9; ++dy) {
        int hr = wave + dy;
#pragma unroll
        for (int t = 0; t < 2; ++t) {
            float i2 = invn2[hr * WCOL + t * 16 + col];
#pragma unroll
            for (int r = 0; r < 4; ++r) {
                int row = quad * 4 + r;
                int dx = t * 16 + col - row;
                if (dx >= 0 && dx <= 8) {
                    float v = acc[dy][t][r] * invn1[wave * 16 + row] * i2 * scale;
                    v = (v >= 0.f) ? v : 0.1f * v;
                    outB[(size_t)(dy * 9 + dx) * HW_ + (w0 + row)] = v;
                }
            }
        }
    }
}

extern "C" void kernel_launch(void* const* d_in, const int* in_sizes, int n_in,
                              void* d_out, int out_size, void* d_ws, size_t ws_size,
                              hipStream_t stream) {
    const float* f1 = (const float*)d_in[0];
    const float* f2 = (const float*)d_in[1];
    float* out = (float*)d_out;
    dim3 grid(W_ / TW, H_ / TH, B_);   // 16 x 16 x 4 = 1024 blocks
    corr81_kernel<<<grid, NTHREADS, 0, stream>>>(f1, f2, out);
}

// Round 4
// 72.920 us; speedup vs baseline: 2.6517x; 1.2182x over previous
//
#include <hip/hip_runtime.h>

#define B_ 4
#define C_ 128
#define H_ 128
#define W_ 256
#define HW_ (H_ * W_)
#define ND 81
#define TH 8          // output rows per block
#define TW 16         // output cols per block
#define HR 16         // f2 halo rows  (TH + 8)
#define WCOL 32       // f2 halo cols
#define KC 32         // channels per LDS chunk (= MFMA K)
#define NCHUNK (C_ / KC)
#define NTHREADS 512

typedef short bf16x8 __attribute__((ext_vector_type(8)));
typedef float f32x4 __attribute__((ext_vector_type(4)));
typedef float f32x4v __attribute__((ext_vector_type(4)));
typedef unsigned int u32x4 __attribute__((ext_vector_type(4)));

// LDS layout: pixel-pair rows of 128 B (2 px x 32ch x 2B).
// Swizzle: XOR bits 4..6 of the FULL byte address by (r & 7) << 4, where
// r = px>>1 lives in bits >=7. Bijective, identical for writer and reader.
// HW-verified in R1/R3.
__device__ __forceinline__ int swz(int px, int byteInHalf) {
    int r = px >> 1;
    int base = (r << 7) + ((px & 1) << 6) + byteInHalf;
    return base ^ ((r & 7) << 4);
}

// fp32 -> bf16 round-to-nearest-even, packed pair (lo = a, hi = b)
__device__ __forceinline__ unsigned int pack_bf16(float a, float b) {
    unsigned int ua = __float_as_uint(a);
    unsigned int ub = __float_as_uint(b);
    ua = (ua + 0x7FFFu + ((ua >> 16) & 1u)) >> 16;
    ub = (ub + 0x7FFFu + ((ub >> 16) & 1u)) >> 16;
    return (ub << 16) | (ua & 0xFFFFu);
}

__device__ __forceinline__ void accum_sq(unsigned int u, float& ss) {
    float lo = __uint_as_float(u << 16);
    float hi = __uint_as_float(u & 0xFFFF0000u);
    ss += lo * lo + hi * hi;
}

__global__ __launch_bounds__(NTHREADS)
void corr81_kernel(const float* __restrict__ f1g, const float* __restrict__ f2g,
                   float* __restrict__ out) {
    __shared__ __align__(16) unsigned short f2s[HR * WCOL * KC];   // 32 KB
    __shared__ __align__(16) unsigned short f1s[TH * TW * KC];     // 8 KB
    __shared__ float invn2[HR * WCOL];
    __shared__ float invn1[TH * TW];

    const int tid  = threadIdx.x;
    const int lane = tid & 63;
    const int wave = tid >> 6;            // 0..7 -> output row within tile
    const int col  = lane & 15;
    const int quad = lane >> 4;

    // ---- XCD-aware block swizzle (T1) ----
    // Dispatch round-robins flat block id across 8 XCDs; remap so each XCD
    // gets a CONTIGUOUS range of 128 original ids (x-fastest -> concurrent
    // blocks on one XCD are spatial neighbors sharing f2 halo in its L2).
    // Bijective: 1024 = 8 * 128 exactly.
    const int flat = blockIdx.x + 16 * blockIdx.y + 256 * blockIdx.z;
    const int orig = (flat & 7) * 128 + (flat >> 3);
    const int w0 = (orig & 15) * TW;
    const int h0 = ((orig >> 4) & 15) * TH;
    const int b  = orig >> 8;
    const size_t inBase = (size_t)b * C_ * HW_;

    // ---- f2 staging tasks: (i 0..3) x per-thread (g2, cp2, rq) ----
    const int g2  = tid & 7;              // 4-px group 0..7
    const int cp2 = (tid >> 3) & 15;      // channel pair 0..15
    const int rq  = tid >> 7;             // row quarter 0..3
    const int gw2 = w0 - 4 + g2 * 4;
    const bool colok2 = (gw2 >= 0) && (gw2 < W_);

    // ---- f1 staging task: one per thread ----
    const int g1  = tid & 3;
    const int cp1 = (tid >> 2) & 15;
    const int r1  = tid >> 6;             // 0..7
    const float* src1 = f1g + inBase + (size_t)(h0 + r1) * W_ + (w0 + g1 * 4);

    // A-fragment address (f1 pixel = wave*16 + col)
    const int aOff = swz(wave * 16 + col, quad * 16);

    f32x4 acc[9][2];
#pragma unroll
    for (int d = 0; d < 9; ++d) {
        acc[d][0] = (f32x4)0.f;
        acc[d][1] = (f32x4)0.f;
    }

    char* f2sW = (char*)f2s;
    char* f1sW = (char*)f1s;
    const char* f2sR = (const char*)f2s;
    const char* f1sR = (const char*)f1s;

    float ss2 = 0.f, ss1 = 0.f;

    // prefetch registers
    f32x4v A0[4], A1[4], B0, B1;

    // ---- prologue: issue chunk-0 loads ----
#pragma unroll
    for (int i = 0; i < 4; ++i) {
        int r  = i * 4 + rq;
        int gh = h0 - 4 + r;
        if (colok2 && gh >= 0 && gh < H_) {
            const float* s = f2g + inBase + (size_t)(cp2 * 2) * HW_ + (size_t)gh * W_ + gw2;
            A0[i] = *(const f32x4v*)s;
            A1[i] = *(const f32x4v*)(s + HW_);
        } else {
            A0[i] = (f32x4v)0.f;
            A1[i] = (f32x4v)0.f;
        }
    }
    {
        const float* s = src1 + (size_t)(cp1 * 2) * HW_;
        B0 = *(const f32x4v*)s;
        B1 = *(const f32x4v*)(s + HW_);
    }

    for (int ch = 0; ch < NCHUNK; ++ch) {
        // ---- pack + write f2 from prefetch regs, then re-issue f2 loads ASAP ----
#pragma unroll
        for (int i = 0; i < 4; ++i) {
            int r = i * 4 + rq;
#pragma unroll
            for (int j = 0; j < 4; ++j) {
                int px = r * 32 + g2 * 4 + j;
                *(unsigned int*)(f2sW + swz(px, cp2 * 4)) = pack_bf16(A0[i][j], A1[i][j]);
            }
        }
        if (ch < NCHUNK - 1) {
            const int kc0 = (ch + 1) * KC;
#pragma unroll
            for (int i = 0; i < 4; ++i) {
                int r  = i * 4 + rq;
                int gh = h0 - 4 + r;
                if (colok2 && gh >= 0 && gh < H_) {
                    const float* s = f2g + inBase + (size_t)(kc0 + cp2 * 2) * HW_ + (size_t)gh * W_ + gw2;
                    A0[i] = *(const f32x4v*)s;
                    A1[i] = *(const f32x4v*)(s + HW_);
                } else {
                    A0[i] = (f32x4v)0.f;
                    A1[i] = (f32x4v)0.f;
                }
            }
        }
        // ---- f1 pack + re-issue ----
#pragma unroll
        for (int j = 0; j < 4; ++j) {
            int px = r1 * 16 + g1 * 4 + j;
            *(unsigned int*)(f1sW + swz(px, cp1 * 4)) = pack_bf16(B0[j], B1[j]);
        }
        if (ch < NCHUNK - 1) {
            const float* s = src1 + (size_t)((ch + 1) * KC + cp1 * 2) * HW_;
            B0 = *(const f32x4v*)s;
            B1 = *(const f32x4v*)(s + HW_);
        }

        __syncthreads();

        // ---- norm accumulation from bf16 LDS ----
#pragma unroll
        for (int j = 0; j < 4; ++j) {
            u32x4 v = *(const u32x4*)(f2sR + swz(tid, j * 16));
            accum_sq(v[0], ss2); accum_sq(v[1], ss2);
            accum_sq(v[2], ss2); accum_sq(v[3], ss2);
        }
        {
            u32x4 v = *(const u32x4*)(f1sR + swz(tid >> 2, (tid & 3) * 16));
            accum_sq(v[0], ss1); accum_sq(v[1], ss1);
            accum_sq(v[2], ss1); accum_sq(v[3], ss1);
        }
        if (ch == NCHUNK - 1) {
            invn2[tid] = 1.f / fmaxf(sqrtf(ss2), 1e-12f);
            float t1 = ss1 + __shfl_xor(ss1, 1);
            t1 += __shfl_xor(t1, 2);
            if ((tid & 3) == 0) invn1[tid >> 2] = 1.f / fmaxf(sqrtf(t1), 1e-12f);
        }

        // ---- MFMA: this wave's f1 row vs 9 dy rows, 2 N-tiles ----
        __builtin_amdgcn_s_setprio(1);
        bf16x8 af = *(const bf16x8*)(f1sR + aOff);
#pragma unroll
        for (int dy = 0; dy < 9; ++dy) {
            int pb = (wave + dy) * WCOL + col;
            bf16x8 b0 = *(const bf16x8*)(f2sR + swz(pb, quad * 16));
            bf16x8 b1 = *(const bf16x8*)(f2sR + swz(pb + 16, quad * 16));
            acc[dy][0] = __builtin_amdgcn_mfma_f32_16x16x32_bf16(af, b0, acc[dy][0], 0, 0, 0);
            acc[dy][1] = __builtin_amdgcn_mfma_f32_16x16x32_bf16(af, b1, acc[dy][1], 0, 0, 0);
        }
        __builtin_amdgcn_s_setprio(0);
        __syncthreads();
    }

    // ---- epilogue: extract band, rescale, leaky-relu, store ----
    const int hOut = h0 + wave;
    float* outB = out + (size_t)b * ND * HW_ + (size_t)hOut * W_;
    const float scale = 1.f / (float)C_;

#pragma unroll
    for (int dy = 0; dy < 9; ++dy) {
        int hr = wave + dy;
#pragma unroll
        for (int t = 0; t < 2; ++t) {
            float i2 = invn2[hr * WCOL + t * 16 + col];
#pragma unroll
            for (int r = 0; r < 4; ++r) {
                int row = quad * 4 + r;
                int dx = t * 16 + col - row;
                if (dx >= 0 && dx <= 8) {
                    float v = acc[dy][t][r] * invn1[wave * 16 + row] * i2 * scale;
                    v = (v >= 0.f) ? v : 0.1f * v;
                    outB[(size_t)(dy * 9 + dx) * HW_ + (w0 + row)] = v;
                }
            }
        }
    }
}

extern "C" void kernel_launch(void* const* d_in, const int* in_sizes, int n_in,
                              void* d_out, int out_size, void* d_ws, size_t ws_size,
                              hipStream_t stream) {
    const float* f1 = (const float*)d_in[0];
    const float* f2 = (const float*)d_in[1];
    float* out = (float*)d_out;
    dim3 grid(W_ / TW, H_ / TH, B_);   // 16 x 16 x 4 = 1024 blocks
    corr81_kernel<<<grid, NTHREADS, 0, stream>>>(f1, f2, out);
}

// Round 5
// 65.455 us; speedup vs baseline: 2.9542x; 1.1141x over previous
//
#include <hip/hip_runtime.h>

#define B_ 4
#define C_ 128
#define H_ 128
#define W_ 256
#define HW_ (H_ * W_)
#define ND 81
#define TH 8          // output rows per block
#define TW 16         // output cols per block
#define HR 16         // f2 halo rows  (TH + 8)
#define WCOL 32       // f2 halo cols
#define KC 32         // channels per LDS chunk (= MFMA K)
#define NCHUNK (C_ / KC)
#define NTHREADS 512

typedef short bf16x8 __attribute__((ext_vector_type(8)));
typedef float f32x4 __attribute__((ext_vector_type(4)));
typedef float f32x4v __attribute__((ext_vector_type(4)));
typedef unsigned int u32x4 __attribute__((ext_vector_type(4)));

// Swizzle (HW-verified R1/R3/R4): XOR bits 4..6 of the full byte address by
// (r & 7) << 4 where r = px>>1 lives in bits >=7. Bijective.
__device__ __forceinline__ int swz(int px, int byteInHalf) {
    int r = px >> 1;
    int base = (r << 7) + ((px & 1) << 6) + byteInHalf;
    return base ^ ((r & 7) << 4);
}

// Native packed fp32->bf16 convert (gfx950). D.lo=bf16(a), D.hi=bf16(b).
// A/B operands use the SAME packing so the MFMA dot is invariant to lo/hi order.
__device__ __forceinline__ unsigned int cvt_pk_bf16(float a, float b) {
    unsigned int r;
    asm("v_cvt_pk_bf16_f32 %0, %1, %2" : "=v"(r) : "v"(a), "v"(b));
    return r;
}

__device__ __forceinline__ void accum_sq(unsigned int u, float& ss) {
    float lo = __uint_as_float(u << 16);
    float hi = __uint_as_float(u & 0xFFFF0000u);
    ss += lo * lo + hi * hi;
}

__global__ __launch_bounds__(NTHREADS)
void corr81_kernel(const float* __restrict__ f1g, const float* __restrict__ f2g,
                   float* __restrict__ out) {
    // Double-buffered staging: exactly 80 KB -> 2 blocks/CU (160 KB LDS).
    __shared__ __align__(16) unsigned short f2s[2][HR * WCOL * KC];  // 2 x 32 KB
    __shared__ __align__(16) unsigned short f1s[2][TH * TW * KC];    // 2 x 8 KB
    // Norm arrays OVERLAY buf0: last buf0 staging write is iter1 (chunk 2);
    // invn written iter3 (post iter2 barrier); epilogue reads post iter3 barrier.
    float* invn2 = (float*)&f2s[0][0];   // 512 floats
    float* invn1 = (float*)&f1s[0][0];   // 128 floats

    const int tid  = threadIdx.x;
    const int lane = tid & 63;
    const int wave = tid >> 6;            // 0..7 -> output row within tile
    const int col  = lane & 15;
    const int quad = lane >> 4;

    // XCD-aware block swizzle (T1, verified R4). Bijective: 1024 = 8*128.
    const int flat = blockIdx.x + 16 * blockIdx.y + 256 * blockIdx.z;
    const int orig = (flat & 7) * 128 + (flat >> 3);
    const int w0 = (orig & 15) * TW;
    const int h0 = ((orig >> 4) & 15) * TH;
    const int b  = orig >> 8;
    const size_t inBase = (size_t)b * C_ * HW_;

    // f2 staging: (i 0..3) x per-thread (g2, cp2, rq)
    const int g2  = tid & 7;
    const int cp2 = (tid >> 3) & 15;
    const int rq  = tid >> 7;
    const int gw2 = w0 - 4 + g2 * 4;
    const bool colok2 = (gw2 >= 0) && (gw2 < W_);

    // f1 staging: one float4-pair per thread
    const int g1  = tid & 3;
    const int cp1 = (tid >> 2) & 15;
    const int r1  = tid >> 6;
    const float* src1 = f1g + inBase + (size_t)(h0 + r1) * W_ + (w0 + g1 * 4);

    const int aOff = swz(wave * 16 + col, quad * 16);

    f32x4 acc[9][2];
#pragma unroll
    for (int d = 0; d < 9; ++d) {
        acc[d][0] = (f32x4)0.f;
        acc[d][1] = (f32x4)0.f;
    }

    float ss2 = 0.f, ss1 = 0.f;
    f32x4v A0[4], A1[4], B0, B1;

    // ---- helpers as macros over compile-time buffer index ----
#define ISSUE_LOADS(kc0)                                                        \
    {                                                                           \
        _Pragma("unroll")                                                       \
        for (int i = 0; i < 4; ++i) {                                           \
            int r  = i * 4 + rq;                                                \
            int gh = h0 - 4 + r;                                                \
            if (colok2 && gh >= 0 && gh < H_) {                                 \
                const float* s = f2g + inBase + (size_t)((kc0) + cp2 * 2) * HW_ \
                                 + (size_t)gh * W_ + gw2;                       \
                A0[i] = *(const f32x4v*)s;                                      \
                A1[i] = *(const f32x4v*)(s + HW_);                              \
            } else {                                                            \
                A0[i] = (f32x4v)0.f;                                            \
                A1[i] = (f32x4v)0.f;                                            \
            }                                                                   \
        }                                                                       \
        const float* s = src1 + (size_t)((kc0) + cp1 * 2) * HW_;                \
        B0 = *(const f32x4v*)s;                                                 \
        B1 = *(const f32x4v*)(s + HW_);                                         \
    }

#define PACK_WRITE(buf)                                                         \
    {                                                                           \
        char* w2 = (char*)&f2s[(buf)][0];                                       \
        char* w1 = (char*)&f1s[(buf)][0];                                       \
        _Pragma("unroll")                                                       \
        for (int i = 0; i < 4; ++i) {                                           \
            int r = i * 4 + rq;                                                 \
            _Pragma("unroll")                                                   \
            for (int j = 0; j < 4; ++j) {                                       \
                int px = r * 32 + g2 * 4 + j;                                   \
                *(unsigned int*)(w2 + swz(px, cp2 * 4)) =                       \
                    cvt_pk_bf16(A0[i][j], A1[i][j]);                            \
            }                                                                   \
        }                                                                       \
        _Pragma("unroll")                                                       \
        for (int j = 0; j < 4; ++j) {                                           \
            int px = r1 * 16 + g1 * 4 + j;                                      \
            *(unsigned int*)(w1 + swz(px, cp1 * 4)) = cvt_pk_bf16(B0[j], B1[j]);\
        }                                                                       \
    }

#define MFMA_PHASE(buf)                                                         \
    {                                                                           \
        const char* r2 = (const char*)&f2s[(buf)][0];                           \
        const char* r1p = (const char*)&f1s[(buf)][0];                          \
        __builtin_amdgcn_s_setprio(1);                                          \
        bf16x8 af = *(const bf16x8*)(r1p + aOff);                               \
        _Pragma("unroll")                                                       \
        for (int dy = 0; dy < 9; ++dy) {                                        \
            int pb = (wave + dy) * WCOL + col;                                  \
            bf16x8 b0 = *(const bf16x8*)(r2 + swz(pb, quad * 16));              \
            bf16x8 b1 = *(const bf16x8*)(r2 + swz(pb + 16, quad * 16));         \
            acc[dy][0] = __builtin_amdgcn_mfma_f32_16x16x32_bf16(af, b0, acc[dy][0], 0, 0, 0); \
            acc[dy][1] = __builtin_amdgcn_mfma_f32_16x16x32_bf16(af, b1, acc[dy][1], 0, 0, 0); \
        }                                                                       \
        __builtin_amdgcn_s_setprio(0);                                          \
    }

#define NORM_PHASE(buf)                                                         \
    {                                                                           \
        const char* r2 = (const char*)&f2s[(buf)][0];                           \
        const char* r1p = (const char*)&f1s[(buf)][0];                          \
        _Pragma("unroll")                                                       \
        for (int j = 0; j < 4; ++j) {                                           \
            u32x4 v = *(const u32x4*)(r2 + swz(tid, j * 16));                   \
            accum_sq(v[0], ss2); accum_sq(v[1], ss2);                           \
            accum_sq(v[2], ss2); accum_sq(v[3], ss2);                           \
        }                                                                       \
        u32x4 v = *(const u32x4*)(r1p + swz(tid >> 2, (tid & 3) * 16));         \
        accum_sq(v[0], ss1); accum_sq(v[1], ss1);                               \
        accum_sq(v[2], ss1); accum_sq(v[3], ss1);                               \
    }

    // ---- prologue: stage chunk 0 into buf0, issue chunk-1 loads ----
    ISSUE_LOADS(0);
    PACK_WRITE(0);
    ISSUE_LOADS(KC);
    __syncthreads();

    // ---- main: one barrier per chunk ----
#pragma unroll
    for (int k = 0; k < NCHUNK; ++k) {
        const int bk = k & 1;
        MFMA_PHASE(bk);
        NORM_PHASE(bk);
        if (k == NCHUNK - 1) {
            invn2[tid] = 1.f / fmaxf(sqrtf(ss2), 1e-12f);
            float t1 = ss1 + __shfl_xor(ss1, 1);
            t1 += __shfl_xor(t1, 2);
            if ((tid & 3) == 0) invn1[tid >> 2] = 1.f / fmaxf(sqrtf(t1), 1e-12f);
        } else {
            PACK_WRITE(bk ^ 1);            // stage chunk k+1 (regs loaded last iter)
            if (k < NCHUNK - 2) ISSUE_LOADS((k + 2) * KC);
        }
        __syncthreads();
    }

    // ---- epilogue: extract band, rescale, leaky-relu, store ----
    const int hOut = h0 + wave;
    float* outB = out + (size_t)b * ND * HW_ + (size_t)hOut * W_;
    const float scale = 1.f / (float)C_;

#pragma unroll
    for (int dy = 0; dy < 9; ++dy) {
        int hr = wave + dy;
#pragma unroll
        for (int t = 0; t < 2; ++t) {
            float i2 = invn2[hr * WCOL + t * 16 + col];
#pragma unroll
            for (int r = 0; r < 4; ++r) {
                int row = quad * 4 + r;
                int dx = t * 16 + col - row;
                if (dx >= 0 && dx <= 8) {
                    float v = acc[dy][t][r] * invn1[wave * 16 + row] * i2 * scale;
                    v = (v >= 0.f) ? v : 0.1f * v;
                    outB[(size_t)(dy * 9 + dx) * HW_ + (w0 + row)] = v;
                }
            }
        }
    }
#undef ISSUE_LOADS
#undef PACK_WRITE
#undef MFMA_PHASE
#undef NORM_PHASE
}

extern "C" void kernel_launch(void* const* d_in, const int* in_sizes, int n_in,
                              void* d_out, int out_size, void* d_ws, size_t ws_size,
                              hipStream_t stream) {
    const float* f1 = (const float*)d_in[0];
    const float* f2 = (const float*)d_in[1];
    float* out = (float*)d_out;
    dim3 grid(W_ / TW, H_ / TH, B_);   // 16 x 16 x 4 = 1024 blocks
    corr81_kernel<<<grid, NTHREADS, 0, stream>>>(f1, f2, out);
}

// Round 6
// 65.320 us; speedup vs baseline: 2.9603x; 1.0021x over previous
//
#include <hip/hip_runtime.h>

#define B_ 4
#define C_ 128
#define H_ 128
#define W_ 256
#define HW_ (H_ * W_)
#define ND 81
#define TH 8          // output rows per block
#define TW 16         // output cols per block
#define HR 16         // f2 halo rows  (TH + 8)
#define WCOL 32       // f2 halo cols
#define KC 32         // channels per LDS chunk (= MFMA K)
#define NCHUNK (C_ / KC)
#define NTHREADS 512

typedef short bf16x8 __attribute__((ext_vector_type(8)));
typedef float f32x4 __attribute__((ext_vector_type(4)));
typedef float f32x4v __attribute__((ext_vector_type(4)));
typedef unsigned int u32x4 __attribute__((ext_vector_type(4)));

// Swizzle (HW-verified R1/R3/R4/R5): XOR bits 4..6 of the full byte address
// by (r & 7) << 4 where r = px>>1 lives in bits >=7. Bijective.
__device__ __forceinline__ int swz(int px, int byteInHalf) {
    int r = px >> 1;
    int base = (r << 7) + ((px & 1) << 6) + byteInHalf;
    return base ^ ((r & 7) << 4);
}

// Native packed fp32->bf16 convert (gfx950). A/B use the same packing so the
// MFMA dot is invariant to lo/hi order.
__device__ __forceinline__ unsigned int cvt_pk_bf16(float a, float b) {
    unsigned int r;
    asm("v_cvt_pk_bf16_f32 %0, %1, %2" : "=v"(r) : "v"(a), "v"(b));
    return r;
}

__device__ __forceinline__ void accum_sq(unsigned int u, float& ss) {
    float lo = __uint_as_float(u << 16);
    float hi = __uint_as_float(u & 0xFFFF0000u);
    ss += lo * lo + hi * hi;
}

// Barrier WITHOUT vmcnt drain (HK 8-phase idiom, guide §5 template):
// lgkmcnt(0) guarantees this wave's ds_reads AND ds_writes completed (LDS
// producer->consumer and WAR on double buffers both safe); global loads
// stay in flight across the barrier — compiler auto-inserts counted vmcnt
// at the consuming register use.
#define BARRIER()                                             \
    do {                                                      \
        asm volatile("s_waitcnt lgkmcnt(0)" ::: "memory");    \
        __builtin_amdgcn_s_barrier();                         \
    } while (0)

__global__ __launch_bounds__(NTHREADS)
void corr81_kernel(const float* __restrict__ f1g, const float* __restrict__ f2g,
                   float* __restrict__ out) {
    // Double-buffered staging: exactly 80 KB -> 2 blocks/CU (160 KB LDS).
    __shared__ __align__(16) unsigned short f2s[2][HR * WCOL * KC];  // 2 x 32 KB
    __shared__ __align__(16) unsigned short f1s[2][TH * TW * KC];    // 2 x 8 KB
    // Norm arrays OVERLAY buf0 (hazard-free: buf0 last staged at k=1, last
    // read at k=2; invn written at k=3 after k=2's barrier; epilogue reads
    // after the final barrier).
    float* invn2 = (float*)&f2s[0][0];   // 512 floats
    float* invn1 = (float*)&f1s[0][0];   // 128 floats

    const int tid  = threadIdx.x;
    const int lane = tid & 63;
    const int wave = tid >> 6;            // 0..7 -> output row within tile
    const int col  = lane & 15;
    const int quad = lane >> 4;

    // XCD-aware block swizzle (T1, verified R4). Bijective: 1024 = 8*128.
    const int flat = blockIdx.x + 16 * blockIdx.y + 256 * blockIdx.z;
    const int orig = (flat & 7) * 128 + (flat >> 3);
    const int w0 = (orig & 15) * TW;
    const int h0 = ((orig >> 4) & 15) * TH;
    const int b  = orig >> 8;
    const size_t inBase = (size_t)b * C_ * HW_;

    // f2 staging: (i 0..3) x per-thread (g2, cp2, rq)
    const int g2  = tid & 7;
    const int cp2 = (tid >> 3) & 15;
    const int rq  = tid >> 7;
    const int gw2 = w0 - 4 + g2 * 4;
    const bool colok2 = (gw2 >= 0) && (gw2 < W_);

    // f1 staging: one float4-pair per thread
    const int g1  = tid & 3;
    const int cp1 = (tid >> 2) & 15;
    const int r1  = tid >> 6;
    const float* src1 = f1g + inBase + (size_t)(h0 + r1) * W_ + (w0 + g1 * 4);

    const int aOff = swz(wave * 16 + col, quad * 16);

    f32x4 acc[9][2];
#pragma unroll
    for (int d = 0; d < 9; ++d) {
        acc[d][0] = (f32x4)0.f;
        acc[d][1] = (f32x4)0.f;
    }

    float ss2 = 0.f, ss1 = 0.f;
    f32x4v A0[4], A1[4], B0, B1;

#define ISSUE_LOADS(kc0)                                                        \
    {                                                                           \
        _Pragma("unroll")                                                       \
        for (int i = 0; i < 4; ++i) {                                           \
            int r  = i * 4 + rq;                                                \
            int gh = h0 - 4 + r;                                                \
            if (colok2 && gh >= 0 && gh < H_) {                                 \
                const float* s = f2g + inBase + (size_t)((kc0) + cp2 * 2) * HW_ \
                                 + (size_t)gh * W_ + gw2;                       \
                A0[i] = *(const f32x4v*)s;                                      \
                A1[i] = *(const f32x4v*)(s + HW_);                              \
            } else {                                                            \
                A0[i] = (f32x4v)0.f;                                            \
                A1[i] = (f32x4v)0.f;                                            \
            }                                                                   \
        }                                                                       \
        const float* s = src1 + (size_t)((kc0) + cp1 * 2) * HW_;                \
        B0 = *(const f32x4v*)s;                                                 \
        B1 = *(const f32x4v*)(s + HW_);                                         \
    }

#define PACK_WRITE(buf)                                                         \
    {                                                                           \
        char* w2 = (char*)&f2s[(buf)][0];                                       \
        char* w1 = (char*)&f1s[(buf)][0];                                       \
        _Pragma("unroll")                                                       \
        for (int i = 0; i < 4; ++i) {                                           \
            int r = i * 4 + rq;                                                 \
            _Pragma("unroll")                                                   \
            for (int j = 0; j < 4; ++j) {                                       \
                int px = r * 32 + g2 * 4 + j;                                   \
                *(unsigned int*)(w2 + swz(px, cp2 * 4)) =                       \
                    cvt_pk_bf16(A0[i][j], A1[i][j]);                            \
            }                                                                   \
        }                                                                       \
        _Pragma("unroll")                                                       \
        for (int j = 0; j < 4; ++j) {                                           \
            int px = r1 * 16 + g1 * 4 + j;                                      \
            *(unsigned int*)(w1 + swz(px, cp1 * 4)) = cvt_pk_bf16(B0[j], B1[j]);\
        }                                                                       \
    }

#define MFMA_PHASE(buf)                                                         \
    {                                                                           \
        const char* r2 = (const char*)&f2s[(buf)][0];                           \
        const char* r1p = (const char*)&f1s[(buf)][0];                          \
        bf16x8 af = *(const bf16x8*)(r1p + aOff);                               \
        _Pragma("unroll")                                                       \
        for (int dy = 0; dy < 9; ++dy) {                                        \
            int pb = (wave + dy) * WCOL + col;                                  \
            bf16x8 b0 = *(const bf16x8*)(r2 + swz(pb, quad * 16));              \
            bf16x8 b1 = *(const bf16x8*)(r2 + swz(pb + 16, quad * 16));         \
            acc[dy][0] = __builtin_amdgcn_mfma_f32_16x16x32_bf16(af, b0, acc[dy][0], 0, 0, 0); \
            acc[dy][1] = __builtin_amdgcn_mfma_f32_16x16x32_bf16(af, b1, acc[dy][1], 0, 0, 0); \
        }                                                                       \
    }

#define NORM_PHASE(buf)                                                         \
    {                                                                           \
        const char* r2 = (const char*)&f2s[(buf)][0];                           \
        const char* r1p = (const char*)&f1s[(buf)][0];                          \
        _Pragma("unroll")                                                       \
        for (int j = 0; j < 4; ++j) {                                           \
            u32x4 v = *(const u32x4*)(r2 + swz(tid, j * 16));                   \
            accum_sq(v[0], ss2); accum_sq(v[1], ss2);                           \
            accum_sq(v[2], ss2); accum_sq(v[3], ss2);                           \
        }                                                                       \
        u32x4 v = *(const u32x4*)(r1p + swz(tid >> 2, (tid & 3) * 16));         \
        accum_sq(v[0], ss1); accum_sq(v[1], ss1);                               \
        accum_sq(v[2], ss1); accum_sq(v[3], ss1);                               \
    }

    // ---- prologue: stage chunk 0 into buf0, issue chunk-1 loads ----
    ISSUE_LOADS(0);
    PACK_WRITE(0);
    ISSUE_LOADS(KC);
    BARRIER();

    // ---- main: one barrier per chunk; loads fly across barriers ----
#pragma unroll
    for (int k = 0; k < NCHUNK; ++k) {
        const int bk = k & 1;
        MFMA_PHASE(bk);
        if (k < NCHUNK - 1) {
            PACK_WRITE(bk ^ 1);            // consumes prefetch regs (WAR before re-issue)
            if (k < NCHUNK - 2) ISSUE_LOADS((k + 2) * KC);
            NORM_PHASE(bk);
        } else {
            NORM_PHASE(bk);
            invn2[tid] = 1.f / fmaxf(sqrtf(ss2), 1e-12f);
            float t1 = ss1 + __shfl_xor(ss1, 1);
            t1 += __shfl_xor(t1, 2);
            if ((tid & 3) == 0) invn1[tid >> 2] = 1.f / fmaxf(sqrtf(t1), 1e-12f);
        }
        BARRIER();
    }

    // ---- epilogue: extract band, rescale, leaky-relu, store ----
    const int hOut = h0 + wave;
    float* outB = out + (size_t)b * ND * HW_ + (size_t)hOut * W_;
    const float scale = 1.f / (float)C_;

#pragma unroll
    for (int dy = 0; dy < 9; ++dy) {
        int hr = wave + dy;
#pragma unroll
        for (int t = 0; t < 2; ++t) {
            float i2 = invn2[hr * WCOL + t * 16 + col];
#pragma unroll
            for (int r = 0; r < 4; ++r) {
                int row = quad * 4 + r;
                int dx = t * 16 + col - row;
                if (dx >= 0 && dx <= 8) {
                    float v = acc[dy][t][r] * invn1[wave * 16 + row] * i2 * scale;
                    v = (v >= 0.f) ? v : 0.1f * v;
                    outB[(size_t)(dy * 9 + dx) * HW_ + (w0 + row)] = v;
                }
            }
        }
    }
#undef ISSUE_LOADS
#undef PACK_WRITE
#undef MFMA_PHASE
#undef NORM_PHASE
}

extern "C" void kernel_launch(void* const* d_in, const int* in_sizes, int n_in,
                              void* d_out, int out_size, void* d_ws, size_t ws_size,
                              hipStream_t stream) {
    const float* f1 = (const float*)d_in[0];
    const float* f2 = (const float*)d_in[1];
    float* out = (float*)d_out;
    dim3 grid(W_ / TW, H_ / TH, B_);   // 16 x 16 x 4 = 1024 blocks
    corr81_kernel<<<grid, NTHREADS, 0, stream>>>(f1, f2, out);
}